// Round 10
// baseline (201.192 us; speedup 1.0000x reference)
//
#include <hip/hip_runtime.h>
#include <hip/hip_bf16.h>

// x: [32, 2048, 17, 3] -> [65536, 51]
// u: panel-major packed bf16: u5[nb(0..5)][m>>2][c(0..127)][m&3], nb=col>>7
//    (PRE-activation f/r).  y: [65536, 51]
static constexpr int M_ROWS = 32 * 2048;   // 65536
static constexpr int MG     = M_ROWS / 4;  // 16384 m-groups
static constexpr int TC     = 64;          // scan chunk length
static constexpr int NCHUNK = 2048 / TC;   // 32

typedef __attribute__((ext_vector_type(8))) __bf16 bf16x8;
typedef __attribute__((ext_vector_type(4))) __bf16 bf16x4;
typedef __attribute__((ext_vector_type(4))) float  f32x4;
typedef __attribute__((ext_vector_type(2))) long long llx2;

#define VM_WAIT(N) asm volatile("s_waitcnt vmcnt(" #N ")" ::: "memory")
#define LGKM_WAIT0 asm volatile("s_waitcnt lgkmcnt(0)" ::: "memory")

__device__ __forceinline__ void async_copy16(void* lds_ptr, const void* g_ptr) {
  __builtin_amdgcn_global_load_lds(
      (const __attribute__((address_space(1))) void*)g_ptr,
      (__attribute__((address_space(3))) void*)lds_ptr, 16, 0, 0);
}

__device__ __forceinline__ float sigmoid_f(float v) {
  return 1.f / (1.f + __expf(-v));
}
__device__ __forceinline__ float tanh_f(float v) {
  v = fminf(fmaxf(v, -15.f), 15.f);
  float e = __expf(-2.f * v);
  return (1.f - e) / (1.f + e);
}

// -------------------------------------------------------------------------
// Prep: W_l [2][256][768] f32 -> Wt [2][768][256] bf16 (transposed)
//       W_out [256][51] f32 -> WtO [128][256] bf16 (transposed, padded)
//       Wc = W_in @ W_l[0]  [51][768] f32-accum -> WcT [768][64] bf16
//       bc[o] = sum_j b_in[j]*W0[j][o] + b_l0[o]   (f32)
// -------------------------------------------------------------------------
__global__ __launch_bounds__(256) void prep_weights(
    const float* __restrict__ Wl, const float* __restrict__ Wout,
    const float* __restrict__ Win, const float* __restrict__ b_in,
    const float* __restrict__ b_l,
    __hip_bfloat16* __restrict__ Wt, __hip_bfloat16* __restrict__ WtO,
    __hip_bfloat16* __restrict__ WcT, float* __restrict__ bc)
{
  const int idx = blockIdx.x * 256 + threadIdx.x;
  const int T1 = 2 * 768 * 256;          // 393216
  const int T2 = T1 + 128 * 256;         // 425984
  const int T4 = T2 + 768 * 64;          // 475136
  const int T5 = T4 + 768;               // 475904
  if (idx < T1) {
    int l = idx / (768 * 256);
    int rem = idx - l * 768 * 256;
    int n = rem >> 8;
    int k = rem & 255;
    Wt[idx] = __float2bfloat16(Wl[(size_t)l * 196608 + (size_t)k * 768 + n]);
  } else if (idx < T2) {
    int i2 = idx - T1;
    int n = i2 >> 8, k = i2 & 255;
    float v = (n < 51) ? Wout[(size_t)k * 51 + n] : 0.f;
    WtO[i2] = __float2bfloat16(v);
  } else if (idx < T4) {
    int i4 = idx - T2;
    int o = i4 >> 6, k = i4 & 63;        // o: 0..767, k: 0..63
    float acc = 0.f;
    if (k < 51) {
      const float* wi = Win + (size_t)k * 256;   // row k of W_in, contiguous
      for (int j = 0; j < 256; ++j)
        acc += wi[j] * Wl[(size_t)j * 768 + o];  // W0 = W_l[0]
    }
    WcT[i4] = __float2bfloat16(acc);
  } else if (idx < T5) {
    int o = idx - T4;
    float acc = b_l[o];                  // b_l0
    for (int j = 0; j < 256; ++j)
      acc += b_in[j] * Wl[(size_t)j * 768 + o];
    bc[o] = acc;
  }
}

// -------------------------------------------------------------------------
// cast/pad x [65536][51] f32 -> xb [65536][64] bf16
// -------------------------------------------------------------------------
__global__ __launch_bounds__(256) void cast_x(
    const float* __restrict__ x, __hip_bfloat16* __restrict__ xb)
{
  const int t = blockIdx.x * 256 + threadIdx.x;  // 524288 = 65536 * 8
  const int row = t >> 3, cg = t & 7;
  __hip_bfloat16 tmp[8];
#pragma unroll
  for (int i = 0; i < 8; ++i) {
    int c = cg * 8 + i;
    float v = (c < 51) ? x[(size_t)row * 51 + c] : 0.f;
    tmp[i] = __float2bfloat16(v);
  }
  *reinterpret_cast<int4*>(&xb[(size_t)row * 64 + cg * 8]) =
      *reinterpret_cast<const int4*>(tmp);
}

// -------------------------------------------------------------------------
// MFMA GEMM, 128x128 tile, 4 waves (2x2), 16x16x32 bf16, K templated.
// A: [M][K] bf16 row-major.  Bt: [N][K] bf16 (pre-transposed weights).
// Grid: 1-D, XCD-chunked (T1).  LDS: double-buffered 32 KB, depth-2
// prefetch, counted vmcnt, raw barriers; round-0 bank swizzle (0 conflicts).
// MODE 0: out = u PANEL-MAJOR u5[nb][m>>2][c][m&3] (nb = n0>>7), +bias.
//   Epilogue 16B-ized: lane pairs (2k,2k+1) share rows / adjacent cols;
//   one 64-bit shfl_xor each for row-groups i and i+1 lets the even lane
//   store row-group i's 16B and the odd lane row-group i+1's 16B.
//   8 x 16B stores/thread (was 16 x 8B).  NBN=6.
// MODE 1: out = y f32 [M][51] row-major, +bias, cols < 51.  NBN=1.
// -------------------------------------------------------------------------
template <int K, int MODE>
__global__ __launch_bounds__(256) void gemm_mfma(
    const __hip_bfloat16* __restrict__ A, const __hip_bfloat16* __restrict__ Bt,
    const float* __restrict__ bias, void* __restrict__ out)
{
  constexpr int NT  = K / 32;
  constexpr int NBN = (MODE == 0) ? 6 : 1;
  __shared__ __hip_bfloat16 lds[16384];  // 32 KB: 2 bufs x (A 4096 + B 4096 el)
  const int tid  = threadIdx.x;
  const int lane = tid & 63;
  const int wave = tid >> 6;
  const int wm = wave >> 1, wn = wave & 1;

  // XCD-chunked block swizzle (T1); bijective: grid % 8 == 0
  const int bid  = blockIdx.x;
  const int xcd  = bid & 7;
  const int slot = bid >> 3;            // 64*NBN slots per XCD
  const int mg   = slot / NBN;
  const int nb   = slot - mg * NBN;
  const int m0   = (xcd * 64 + mg) * 128;
  const int n0   = nb * 128;

  // staging: lane -> (row = lane>>2, swizzled source col-block)
  const int srow = lane >> 2;
  const int scb  = ((lane & 3) - ((lane >> 3) & 3)) & 3;
  const int c0   = wave * 2;  // this wave stages 16-row chunks c0, c0+1 of A and B

  const __hip_bfloat16* gA = A + (size_t)(m0 + c0 * 16 + srow) * K + scb * 8;
  const __hip_bfloat16* gB = Bt + (size_t)(n0 + c0 * 16 + srow) * K + scb * 8;

  f32x4 acc[4][4] = {};

  const int rsel = lane & 15;
  const int cls  = ((lane >> 4) + ((lane >> 1) & 3)) & 3;  // read-side swizzle class

  auto stage = [&](int kt, int buf) {
    char* la = (char*)lds + buf * 16384 + c0 * 1024;
    const __hip_bfloat16* a = gA + kt * 32;
    async_copy16(la, a);
    async_copy16(la + 1024, a + 16 * K);
    char* lb = (char*)lds + buf * 16384 + 8192 + c0 * 1024;
    const __hip_bfloat16* b = gB + kt * 32;
    async_copy16(lb, b);
    async_copy16(lb + 1024, b + 16 * K);
  };

  stage(0, 0);
  stage(1, 1);

#pragma unroll
  for (int kt = 0; kt < NT; ++kt) {
    // Outstanding here: tiles kt, kt+1 (8 loads).  Drain to tile kt landed.
    if (kt < NT - 1) { VM_WAIT(4); } else { VM_WAIT(0); }
    __builtin_amdgcn_s_barrier();

    const __hip_bfloat16* base = lds + (kt & 1) * 8192;
    bf16x8 af[4], bg[4];
#pragma unroll
    for (int i = 0; i < 4; ++i) {
      af[i] = *reinterpret_cast<const bf16x8*>(
          base + (wm * 64 + i * 16 + rsel) * 32 + cls * 8);
      bg[i] = *reinterpret_cast<const bf16x8*>(
          base + 4096 + (wn * 64 + i * 16 + rsel) * 32 + cls * 8);
    }
    LGKM_WAIT0;                          // frags in regs
    __builtin_amdgcn_sched_barrier(0);   // rule 18
    __builtin_amdgcn_s_barrier();        // all waves done reading buf kt&1

    if (kt + 2 < NT) stage(kt + 2, kt & 1);  // just-freed buffer

    __builtin_amdgcn_s_setprio(1);
#pragma unroll
    for (int i = 0; i < 4; ++i)
#pragma unroll
      for (int j = 0; j < 4; ++j)
        acc[i][j] = __builtin_amdgcn_mfma_f32_16x16x32_bf16(af[i], bg[j],
                                                            acc[i][j], 0, 0, 0);
    __builtin_amdgcn_s_setprio(0);
  }

  // Epilogue.  C/D layout: col = lane&15, row = (lane>>4)*4 + e  [verified m89]
  const int rbase = m0 + wm * 64 + (lane >> 4) * 4;   // multiple of 4
  const int cbase = n0 + wn * 64 + (lane & 15);
  if (MODE == 0) {
    const int odd = lane & 1;
#pragma unroll
    for (int ip = 0; ip < 2; ++ip) {
      const int i0 = ip * 2;
#pragma unroll
      for (int j = 0; j < 4; ++j) {
        const int col = cbase + j * 16;
        const float bsc = bias[col];
        bf16x4 v0, v1;
#pragma unroll
        for (int e = 0; e < 4; ++e) {
          v0[e] = (__bf16)(acc[i0][j][e] + bsc);
          v1[e] = (__bf16)(acc[i0 + 1][j][e] + bsc);
        }
        long long a0 = __builtin_bit_cast(long long, v0);
        long long a1 = __builtin_bit_cast(long long, v1);
        long long p0 = __shfl_xor(a0, 1);  // partner's row-group i0 (adj col)
        long long p1 = __shfl_xor(a1, 1);  // partner's row-group i0+1
        const int ii = i0 + odd;           // even lane: i0; odd lane: i0+1
        const long long lo = odd ? p1 : a0;  // even col of the pair
        const long long hi = odd ? a1 : p0;  // odd col of the pair
        const int ce = (col & 127) - odd;
        __hip_bfloat16* p = (__hip_bfloat16*)out +
            ((size_t)(n0 >> 7) * MG + ((rbase + ii * 16) >> 2)) * 512 + ce * 4;
        llx2 w; w.x = lo; w.y = hi;
        *reinterpret_cast<llx2*>(p) = w;   // 16B store
      }
    }
  } else {
#pragma unroll
    for (int i = 0; i < 4; ++i) {
#pragma unroll
      for (int j = 0; j < 4; ++j) {
#pragma unroll
        for (int e = 0; e < 4; ++e) {
          const int row = rbase + i * 16 + e;
          const int col = cbase + j * 16;
          if (col < 51) {
            ((float*)out)[(size_t)row * 51 + col] = acc[i][j][e] + bias[col];
          }
        }
      }
    }
  }
}

// -------------------------------------------------------------------------
// Chunked linear-recurrence scan over panel-major u — 16B-granule version.
// Thread owns 2 adjacent h columns (16B bf16x8 loads); block = 2 chunks.
// u5[nb][m>>2][c][m&3]: col = gate*256 + h; nb = col>>7, c = col&127.
// sigmoid applied here (scans BW-bound, VALU idle).
// -------------------------------------------------------------------------
__global__ __launch_bounds__(256) void scan_p1(
    const __hip_bfloat16* __restrict__ u, float* __restrict__ Pa,
    float* __restrict__ Pb)
{
  const int blk = blockIdx.x;            // 512 = 32 b x 16 chunk-pairs
  const int b = blk >> 4, cp = blk & 15;
  const int tid = threadIdx.x;
  const int sub = tid >> 7;              // which chunk of the pair
  const int tp  = tid & 127;
  const int ch  = cp * 2 + sub;
  const int h0  = tp * 2;                // h0, h0+1
  const int nb  = h0 >> 7;
  const int cc  = (h0 & 127) * 4;        // element offset; 16B-aligned
  const int m4base = (b * 2048 + ch * TC) >> 2;
  const __hip_bfloat16* px = u + ((size_t)nb * MG + m4base) * 512 + cc;
  const __hip_bfloat16* pf = u + ((size_t)(2 + nb) * MG + m4base) * 512 + cc;
  float cA = 0.f, cB = 0.f, aA = 1.f, aB = 1.f;
#pragma unroll 4
  for (int t4 = 0; t4 < TC / 4; ++t4) {
    bf16x8 xv = *reinterpret_cast<const bf16x8*>(px + t4 * 512);
    bf16x8 fv = *reinterpret_cast<const bf16x8*>(pf + t4 * 512);
#pragma unroll
    for (int e = 0; e < 4; ++e) {
      float f0 = sigmoid_f((float)fv[e]);
      float x0 = (float)xv[e];
      cA = f0 * cA + (1.f - f0) * x0;  aA *= f0;
      float f1 = sigmoid_f((float)fv[4 + e]);
      float x1 = (float)xv[4 + e];
      cB = f1 * cB + (1.f - f1) * x1;  aB *= f1;
    }
  }
  const int o = (b * NCHUNK + ch) * 256 + h0;   // h0 even -> 8B aligned
  *reinterpret_cast<float2*>(Pa + o) = make_float2(aA, aB);
  *reinterpret_cast<float2*>(Pb + o) = make_float2(cA, cB);
}

__global__ __launch_bounds__(256) void scan_p2(
    const float* __restrict__ Pa, const float* __restrict__ Pb,
    float* __restrict__ Cin)
{
  const int idx = blockIdx.x * 256 + threadIdx.x;  // 8192 = 32 b * 256 h
  const int b = idx >> 8, h = idx & 255;
  float c = 0.f;
  for (int ch = 0; ch < NCHUNK; ++ch) {
    const int o = (b * NCHUNK + ch) * 256 + h;
    Cin[o] = c;
    c = Pa[o] * c + Pb[o];
  }
}

// p3: 16B loads (2 h/thread) + 16B stores via 4 KB LDS transpose tile.
__global__ __launch_bounds__(256) void scan_p3(
    const __hip_bfloat16* __restrict__ u, const float* __restrict__ Cin,
    __hip_bfloat16* __restrict__ hout)
{
  __shared__ __hip_bfloat16 tile[2][4][256];   // [chunk][t-of-4][h] = 4 KB
  const int blk = blockIdx.x;            // 512 = 32 b x 16 chunk-pairs
  const int b = blk >> 4, cp = blk & 15;
  const int tid = threadIdx.x;
  const int sub = tid >> 7;
  const int tp  = tid & 127;
  const int ch  = cp * 2 + sub;
  const int h0  = tp * 2;
  const int nb  = h0 >> 7;
  const int cc  = (h0 & 127) * 4;
  const int m4base = (b * 2048 + ch * TC) >> 2;
  const __hip_bfloat16* px = u + ((size_t)nb * MG + m4base) * 512 + cc;
  const __hip_bfloat16* pf = u + ((size_t)(2 + nb) * MG + m4base) * 512 + cc;
  const __hip_bfloat16* pr = u + ((size_t)(4 + nb) * MG + m4base) * 512 + cc;
  const int o = (b * NCHUNK + ch) * 256 + h0;
  float cA = Cin[o], cB = Cin[o + 1];

  // copy-out mapping: 256 threads x 16B = 4 KB per 4-t group
  const int e2 = (tid >> 5) & 3;
  const int hg = (tid & 31) * 8;
  __hip_bfloat16* ob2 =
      hout + (size_t)(b * 2048 + (cp * 2 + (tid >> 7)) * TC) * 256;

  for (int t4 = 0; t4 < TC / 4; ++t4) {
    bf16x8 xv = *reinterpret_cast<const bf16x8*>(px + t4 * 512);
    bf16x8 fv = *reinterpret_cast<const bf16x8*>(pf + t4 * 512);
    bf16x8 rv = *reinterpret_cast<const bf16x8*>(pr + t4 * 512);
#pragma unroll
    for (int e = 0; e < 4; ++e) {
      float x0 = (float)xv[e];
      float f0 = sigmoid_f((float)fv[e]);
      float r0 = sigmoid_f((float)rv[e]);
      cA = f0 * cA + (1.f - f0) * x0;
      tile[sub][e][h0] = __float2bfloat16(r0 * tanh_f(cA) + (1.f - r0) * x0);
      float x1 = (float)xv[4 + e];
      float f1 = sigmoid_f((float)fv[4 + e]);
      float r1 = sigmoid_f((float)rv[4 + e]);
      cB = f1 * cB + (1.f - f1) * x1;
      tile[sub][e][h0 + 1] =
          __float2bfloat16(r1 * tanh_f(cB) + (1.f - r1) * x1);
    }
    __syncthreads();
    bf16x8 w = *reinterpret_cast<const bf16x8*>(&tile[tid >> 7][e2][hg]);
    *reinterpret_cast<bf16x8*>(ob2 + (t4 * 4 + e2) * 256 + hg) = w;
    __syncthreads();
  }
}

// -------------------------------------------------------------------------
extern "C" void kernel_launch(void* const* d_in, const int* in_sizes, int n_in,
                              void* d_out, int out_size, void* d_ws, size_t ws_size,
                              hipStream_t stream) {
  const float* x     = (const float*)d_in[0];
  const float* W_in  = (const float*)d_in[1];
  const float* b_in  = (const float*)d_in[2];
  const float* W_l   = (const float*)d_in[3];
  const float* b_l   = (const float*)d_in[4];
  const float* W_out = (const float*)d_in[5];
  const float* b_out = (const float*)d_in[6];

  char* ws = (char*)d_ws;
  const size_t U_B    = (size_t)M_ROWS * 768 * 2;      // 100,663,296
  const size_t H_B    = (size_t)M_ROWS * 256 * 2;      //  33,554,432
  const size_t WT_B   = (size_t)2 * 768 * 256 * 2;     //     786,432
  const size_t WTO_B  = (size_t)128 * 256 * 2;         //      65,536
  const size_t WC_B   = (size_t)768 * 64 * 2;          //      98,304
  const size_t BC_B   = (size_t)768 * 4;               //       3,072
  const size_t XB_B   = (size_t)M_ROWS * 64 * 2;       //   8,388,608
  const size_t AB_B   = (size_t)32 * NCHUNK * 256 * 4; //   1,048,576

  size_t off = 0;
  __hip_bfloat16* u    = (__hip_bfloat16*)(ws + off); off += U_B;
  __hip_bfloat16* hA   = (__hip_bfloat16*)(ws + off); off += H_B;
  __hip_bfloat16* hB   = (__hip_bfloat16*)(ws + off); off += H_B;
  __hip_bfloat16* Wt   = (__hip_bfloat16*)(ws + off); off += WT_B;
  __hip_bfloat16* WtO  = (__hip_bfloat16*)(ws + off); off += WTO_B;
  __hip_bfloat16* WcT  = (__hip_bfloat16*)(ws + off); off += WC_B;
  float* bc  = (float*)(ws + off); off += BC_B;
  __hip_bfloat16* xb   = (__hip_bfloat16*)(ws + off); off += XB_B;
  float* Pa  = (float*)(ws + off); off += AB_B;
  float* Pb  = (float*)(ws + off); off += AB_B;
  float* Cin = (float*)(ws + off); off += AB_B;

  prep_weights<<<1860, 256, 0, stream>>>(W_l, W_out, W_in, b_in, b_l,
                                         Wt, WtO, WcT, bc);
  cast_x<<<M_ROWS * 8 / 256, 256, 0, stream>>>(x, xb);

  // layer 0: u = xb @ WcT^T + bc   (input GEMM folded in; K=64)
  gemm_mfma<64, 0><<<M_ROWS / 128 * 6, 256, 0, stream>>>(xb, WcT, bc, u);
  scan_p1<<<32 * NCHUNK / 2, 256, 0, stream>>>(u, Pa, Pb);
  scan_p2<<<32, 256, 0, stream>>>(Pa, Pb, Cin);
  scan_p3<<<32 * NCHUNK / 2, 256, 0, stream>>>(u, Cin, hB);

  // layer 1
  gemm_mfma<256, 0><<<M_ROWS / 128 * 6, 256, 0, stream>>>(hB, Wt + 768 * 256,
                                                          b_l + 768, u);
  scan_p1<<<32 * NCHUNK / 2, 256, 0, stream>>>(u, Pa, Pb);
  scan_p2<<<32, 256, 0, stream>>>(Pa, Pb, Cin);
  scan_p3<<<32 * NCHUNK / 2, 256, 0, stream>>>(u, Cin, hA);

  // output GEMM
  gemm_mfma<256, 1><<<M_ROWS / 128, 256, 0, stream>>>(hA, WtO, b_out, d_out);

  (void)in_sizes; (void)n_in; (void)out_size; (void)ws_size;
}

// Round 11
// 190.230 us; speedup vs baseline: 1.0576x; 1.0576x over previous
//
#include <hip/hip_runtime.h>
#include <hip/hip_bf16.h>

// x: [32, 2048, 17, 3] -> [65536, 51]
// u: panel-major packed bf16: u5[nb(0..5)][m>>2][c(0..127)][m&3], nb=col>>7
//    (PRE-activation f/r).  y: [65536, 51]
static constexpr int M_ROWS = 32 * 2048;   // 65536
static constexpr int MG     = M_ROWS / 4;  // 16384 m-groups
static constexpr int TC     = 64;          // scan chunk length
static constexpr int NCHUNK = 2048 / TC;   // 32

typedef __attribute__((ext_vector_type(8))) __bf16 bf16x8;
typedef __attribute__((ext_vector_type(4))) __bf16 bf16x4;
typedef __attribute__((ext_vector_type(4))) float  f32x4;

#define VM_WAIT(N) asm volatile("s_waitcnt vmcnt(" #N ")" ::: "memory")
#define LGKM_WAIT0 asm volatile("s_waitcnt lgkmcnt(0)" ::: "memory")

__device__ __forceinline__ void async_copy16(void* lds_ptr, const void* g_ptr) {
  __builtin_amdgcn_global_load_lds(
      (const __attribute__((address_space(1))) void*)g_ptr,
      (__attribute__((address_space(3))) void*)lds_ptr, 16, 0, 0);
}

__device__ __forceinline__ float sigmoid_f(float v) {
  return 1.f / (1.f + __expf(-v));
}
__device__ __forceinline__ float tanh_f(float v) {
  v = fminf(fmaxf(v, -15.f), 15.f);
  float e = __expf(-2.f * v);
  return (1.f - e) / (1.f + e);
}

// -------------------------------------------------------------------------
// Prep: W_l [2][256][768] f32 -> Wt [2][768][256] bf16 (transposed)
//       W_out [256][51] f32 -> WtO [128][256] bf16 (transposed, padded)
//       Wc = W_in @ W_l[0]  [51][768] f32-accum -> WcT [768][64] bf16
//       bc[o] = sum_j b_in[j]*W0[j][o] + b_l0[o]   (f32)
// -------------------------------------------------------------------------
__global__ __launch_bounds__(256) void prep_weights(
    const float* __restrict__ Wl, const float* __restrict__ Wout,
    const float* __restrict__ Win, const float* __restrict__ b_in,
    const float* __restrict__ b_l,
    __hip_bfloat16* __restrict__ Wt, __hip_bfloat16* __restrict__ WtO,
    __hip_bfloat16* __restrict__ WcT, float* __restrict__ bc)
{
  const int idx = blockIdx.x * 256 + threadIdx.x;
  const int T1 = 2 * 768 * 256;          // 393216
  const int T2 = T1 + 128 * 256;         // 425984
  const int T4 = T2 + 768 * 64;          // 475136
  const int T5 = T4 + 768;               // 475904
  if (idx < T1) {
    int l = idx / (768 * 256);
    int rem = idx - l * 768 * 256;
    int n = rem >> 8;
    int k = rem & 255;
    Wt[idx] = __float2bfloat16(Wl[(size_t)l * 196608 + (size_t)k * 768 + n]);
  } else if (idx < T2) {
    int i2 = idx - T1;
    int n = i2 >> 8, k = i2 & 255;
    float v = (n < 51) ? Wout[(size_t)k * 51 + n] : 0.f;
    WtO[i2] = __float2bfloat16(v);
  } else if (idx < T4) {
    int i4 = idx - T2;
    int o = i4 >> 6, k = i4 & 63;        // o: 0..767, k: 0..63
    float acc = 0.f;
    if (k < 51) {
      const float* wi = Win + (size_t)k * 256;   // row k of W_in, contiguous
      for (int j = 0; j < 256; ++j)
        acc += wi[j] * Wl[(size_t)j * 768 + o];  // W0 = W_l[0]
    }
    WcT[i4] = __float2bfloat16(acc);
  } else if (idx < T5) {
    int o = idx - T4;
    float acc = b_l[o];                  // b_l0
    for (int j = 0; j < 256; ++j)
      acc += b_in[j] * Wl[(size_t)j * 768 + o];
    bc[o] = acc;
  }
}

// -------------------------------------------------------------------------
// cast/pad x [65536][51] f32 -> xb [65536][64] bf16
// -------------------------------------------------------------------------
__global__ __launch_bounds__(256) void cast_x(
    const float* __restrict__ x, __hip_bfloat16* __restrict__ xb)
{
  const int t = blockIdx.x * 256 + threadIdx.x;  // 524288 = 65536 * 8
  const int row = t >> 3, cg = t & 7;
  __hip_bfloat16 tmp[8];
#pragma unroll
  for (int i = 0; i < 8; ++i) {
    int c = cg * 8 + i;
    float v = (c < 51) ? x[(size_t)row * 51 + c] : 0.f;
    tmp[i] = __float2bfloat16(v);
  }
  *reinterpret_cast<int4*>(&xb[(size_t)row * 64 + cg * 8]) =
      *reinterpret_cast<const int4*>(tmp);
}

// -------------------------------------------------------------------------
// PERSISTENT MFMA GEMM, 128x128 tile, 4 waves (2x2), 16x16x32 bf16.
// A: [M][K] bf16 row-major.  Bt: [N][K] bf16 (pre-transposed weights).
// Grid = total_tiles / TILES blocks; block b processes tiles
// {b, b+grid, b+2*grid} — ONE generation, zero block turnover (4 blocks/CU
// at 32 KB LDS).  The counted-vmcnt pipeline extends ACROSS tiles: during
// tile g's last two K-steps the block stages tile g+1's first two K-tiles;
// the epilogue's 8 stores are issued and left in flight (vmcnt retires in
// order, so at next tile's kt<2 the wait is vmcnt(12) = 2 stages + 8
// stores; kt==2's vmcnt(4) drains the then-old stores).  One cold-start
// latency per block instead of one per tile; tile g's stores hide under
// tile g+1's loads+MFMA.
// LDS layout + bank swizzle + XCD-chunked tile->(m0,n0) map identical to
// round-9 (measured: 0 conflicts, FETCH 83->19 MB).
// MODE 0: out = u PANEL-MAJOR u5[nb][m>>2][c][m&3] (nb = n0>>7), +bias.
// MODE 1: out = y f32 [M][51] row-major, +bias, cols < 51.  NBN=1.
// -------------------------------------------------------------------------
template <int K, int MODE, int TILES>
__global__ __launch_bounds__(256) void gemm_mfma(
    const __hip_bfloat16* __restrict__ A, const __hip_bfloat16* __restrict__ Bt,
    const float* __restrict__ bias, void* __restrict__ out)
{
  constexpr int NT  = K / 32;            // K-steps per tile (even)
  constexpr int NBN = (MODE == 0) ? 6 : 1;
  __shared__ __hip_bfloat16 lds[16384];  // 32 KB: 2 bufs x (A 4096 + B 4096 el)
  const int tid  = threadIdx.x;
  const int lane = tid & 63;
  const int wave = tid >> 6;
  const int wm = wave >> 1, wn = wave & 1;

  const int srow = lane >> 2;
  const int scb  = ((lane & 3) - ((lane >> 3) & 3)) & 3;
  const int c0   = wave * 2;
  const int rsel = lane & 15;
  const int cls  = ((lane >> 4) + ((lane >> 1) & 3)) & 3;

  // tile index -> XCD-chunked (m0, n0) + staging base pointers
  auto setTile = [&](int t, int& m0, int& n0, const __hip_bfloat16*& gA,
                     const __hip_bfloat16*& gB) {
    const int xcd = t & 7;
    const int slot = t >> 3;
    const int mg = slot / NBN;
    const int nb = slot - mg * NBN;
    m0 = (xcd * 64 + mg) * 128;
    n0 = nb * 128;
    gA = A + (size_t)(m0 + c0 * 16 + srow) * K + scb * 8;
    gB = Bt + (size_t)(n0 + c0 * 16 + srow) * K + scb * 8;
  };

  auto stage = [&](const __hip_bfloat16* a0, const __hip_bfloat16* b0, int kt,
                   int buf) {
    char* la = (char*)lds + buf * 16384 + c0 * 1024;
    const __hip_bfloat16* a = a0 + kt * 32;
    async_copy16(la, a);
    async_copy16(la + 1024, a + 16 * K);
    char* lb = (char*)lds + buf * 16384 + 8192 + c0 * 1024;
    const __hip_bfloat16* b = b0 + kt * 32;
    async_copy16(lb, b);
    async_copy16(lb + 1024, b + 16 * K);
  };

  f32x4 acc[4][4] = {};

  int m0c, n0c;
  const __hip_bfloat16 *gAc, *gBc;
  setTile(blockIdx.x, m0c, n0c, gAc, gBc);
  stage(gAc, gBc, 0, 0);
  stage(gAc, gBc, 1, 1);

#pragma unroll
  for (int g = 0; g < TILES; ++g) {
    int m0n = 0, n0n = 0;
    const __hip_bfloat16* gAn = nullptr;
    const __hip_bfloat16* gBn = nullptr;
    if (g + 1 < TILES)
      setTile(blockIdx.x + (g + 1) * gridDim.x, m0n, n0n, gAn, gBn);

#pragma unroll
    for (int kt = 0; kt < NT; ++kt) {
      const int s = g * NT + kt;
      // Wait for stage(s).  In-flight: stage(s+1) always; plus the previous
      // tile's 8 epilogue stores at kt<2 (issued after stage(s)/stage(s+1)
      // or between them — stage(s) is always the oldest unretired group,
      // so vmcnt(12) retires exactly through it).  kt==2's vmcnt(4) drains
      // the then-old stores.  Final step drains everything.
      if (g == TILES - 1 && kt == NT - 1) { VM_WAIT(0); }
      else if (g > 0 && kt < 2)           { VM_WAIT(12); }
      else                                { VM_WAIT(4); }
      __builtin_amdgcn_s_barrier();

      const __hip_bfloat16* base = lds + (s & 1) * 8192;
      bf16x8 af[4], bg[4];
#pragma unroll
      for (int i = 0; i < 4; ++i) {
        af[i] = *reinterpret_cast<const bf16x8*>(
            base + (wm * 64 + i * 16 + rsel) * 32 + cls * 8);
        bg[i] = *reinterpret_cast<const bf16x8*>(
            base + 4096 + (wn * 64 + i * 16 + rsel) * 32 + cls * 8);
      }
      LGKM_WAIT0;                          // frags in regs
      __builtin_amdgcn_sched_barrier(0);   // rule 18
      __builtin_amdgcn_s_barrier();        // all waves done reading buf s&1

      if (s + 2 < NT * TILES) {            // stage step s+2 into freed buf
        if (kt + 2 < NT) stage(gAc, gBc, kt + 2, s & 1);
        else             stage(gAn, gBn, kt + 2 - NT, s & 1);
      }

      __builtin_amdgcn_s_setprio(1);
#pragma unroll
      for (int i = 0; i < 4; ++i)
#pragma unroll
        for (int j = 0; j < 4; ++j)
          acc[i][j] = __builtin_amdgcn_mfma_f32_16x16x32_bf16(
              af[i], bg[j], acc[i][j], 0, 0, 0);
      __builtin_amdgcn_s_setprio(0);
    }

    // ---- Epilogue for tile g (stores left in flight; next tile's waits
    // account for them).  C/D: col = lane&15, row = (lane>>4)*4 + e  [m89]
    {
      const int rbase = m0c + wm * 64 + (lane >> 4) * 4;  // multiple of 4
      const int cbase = n0c + wn * 64 + (lane & 15);
#pragma unroll
      for (int i = 0; i < 4; ++i) {
#pragma unroll
        for (int j = 0; j < 4; ++j) {
          if (MODE == 0) {
            const int col = cbase + j * 16;
            const float b = bias[col];
            bf16x4 v;
#pragma unroll
            for (int e = 0; e < 4; ++e)
              v[e] = (__bf16)(acc[i][j][e] + b);
            __hip_bfloat16* p = (__hip_bfloat16*)out +
                ((size_t)(n0c >> 7) * MG + ((rbase + i * 16) >> 2)) * 512 +
                (col & 127) * 4;
            *reinterpret_cast<bf16x4*>(p) = v;
          } else {
#pragma unroll
            for (int e = 0; e < 4; ++e) {
              const int row = rbase + i * 16 + e;
              const int col = cbase + j * 16;
              if (col < 51) {
                ((float*)out)[(size_t)row * 51 + col] =
                    acc[i][j][e] + bias[col];
              }
            }
          }
          acc[i][j] = f32x4{0.f, 0.f, 0.f, 0.f};
        }
      }
    }
    m0c = m0n; n0c = n0n; gAc = gAn; gBc = gBn;
  }
}

// -------------------------------------------------------------------------
// Chunked linear-recurrence scan over panel-major u (round-9 verified).
// u5[nb][m>>2][c][m&3]: col = gate*256 + h; nb = col>>7, c = col&127.
// sigmoid applied here (scans BW-bound, VALU idle).
// -------------------------------------------------------------------------
__global__ __launch_bounds__(256) void scan_p1(
    const __hip_bfloat16* __restrict__ u, float* __restrict__ Pa,
    float* __restrict__ Pb)
{
  const int blk = blockIdx.x;
  const int b = blk >> 5, ch = blk & 31;
  const int h = threadIdx.x;
  const int m4base = (b * 2048 + ch * TC) >> 2;
  const int cc = (h & 127) * 4;
  const __hip_bfloat16* px =
      u + ((size_t)(h >> 7) * MG + m4base) * 512 + cc;          // x_tilde
  const __hip_bfloat16* pf =
      u + ((size_t)(2 + (h >> 7)) * MG + m4base) * 512 + cc;    // f_pre
  float c = 0.f, a = 1.f;
#pragma unroll 4
  for (int t4 = 0; t4 < TC / 4; ++t4) {
    bf16x4 xv = *reinterpret_cast<const bf16x4*>(px + t4 * 512);
    bf16x4 fv = *reinterpret_cast<const bf16x4*>(pf + t4 * 512);
#pragma unroll
    for (int e = 0; e < 4; ++e) {
      float f  = sigmoid_f((float)fv[e]);
      float xt = (float)xv[e];
      c = f * c + (1.f - f) * xt;
      a *= f;
    }
  }
  const int o = (b * NCHUNK + ch) * 256 + h;
  Pa[o] = a;
  Pb[o] = c;
}

__global__ __launch_bounds__(256) void scan_p2(
    const float* __restrict__ Pa, const float* __restrict__ Pb,
    float* __restrict__ Cin)
{
  const int idx = blockIdx.x * 256 + threadIdx.x;  // 8192 = 32 b * 256 h
  const int b = idx >> 8, h = idx & 255;
  float c = 0.f;
  for (int ch = 0; ch < NCHUNK; ++ch) {
    const int o = (b * NCHUNK + ch) * 256 + h;
    Cin[o] = c;
    c = Pa[o] * c + Pb[o];
  }
}

__global__ __launch_bounds__(256) void scan_p3(
    const __hip_bfloat16* __restrict__ u, const float* __restrict__ Cin,
    __hip_bfloat16* __restrict__ hout)
{
  const int blk = blockIdx.x;
  const int b = blk >> 5, ch = blk & 31;
  const int h = threadIdx.x;
  const int m4base = (b * 2048 + ch * TC) >> 2;
  const int cc = (h & 127) * 4;
  const __hip_bfloat16* px =
      u + ((size_t)(h >> 7) * MG + m4base) * 512 + cc;
  const __hip_bfloat16* pf =
      u + ((size_t)(2 + (h >> 7)) * MG + m4base) * 512 + cc;
  const __hip_bfloat16* pr =
      u + ((size_t)(4 + (h >> 7)) * MG + m4base) * 512 + cc;
  __hip_bfloat16* ob = hout + (size_t)(b * 2048 + ch * TC) * 256;
  float c = Cin[(b * NCHUNK + ch) * 256 + h];
#pragma unroll 2
  for (int t4 = 0; t4 < TC / 4; ++t4) {
    bf16x4 xv = *reinterpret_cast<const bf16x4*>(px + t4 * 512);
    bf16x4 fv = *reinterpret_cast<const bf16x4*>(pf + t4 * 512);
    bf16x4 rv = *reinterpret_cast<const bf16x4*>(pr + t4 * 512);
#pragma unroll
    for (int e = 0; e < 4; ++e) {
      float xt = (float)xv[e];
      float f  = sigmoid_f((float)fv[e]);
      float r  = sigmoid_f((float)rv[e]);
      c = f * c + (1.f - f) * xt;
      float th = tanh_f(c);
      ob[(t4 * 4 + e) * 256 + h] = __float2bfloat16(r * th + (1.f - r) * xt);
    }
  }
}

// -------------------------------------------------------------------------
extern "C" void kernel_launch(void* const* d_in, const int* in_sizes, int n_in,
                              void* d_out, int out_size, void* d_ws, size_t ws_size,
                              hipStream_t stream) {
  const float* x     = (const float*)d_in[0];
  const float* W_in  = (const float*)d_in[1];
  const float* b_in  = (const float*)d_in[2];
  const float* W_l   = (const float*)d_in[3];
  const float* b_l   = (const float*)d_in[4];
  const float* W_out = (const float*)d_in[5];
  const float* b_out = (const float*)d_in[6];

  char* ws = (char*)d_ws;
  const size_t U_B    = (size_t)M_ROWS * 768 * 2;      // 100,663,296
  const size_t H_B    = (size_t)M_ROWS * 256 * 2;      //  33,554,432
  const size_t WT_B   = (size_t)2 * 768 * 256 * 2;     //     786,432
  const size_t WTO_B  = (size_t)128 * 256 * 2;         //      65,536
  const size_t WC_B   = (size_t)768 * 64 * 2;          //      98,304
  const size_t BC_B   = (size_t)768 * 4;               //       3,072
  const size_t XB_B   = (size_t)M_ROWS * 64 * 2;       //   8,388,608
  const size_t AB_B   = (size_t)32 * NCHUNK * 256 * 4; //   1,048,576

  size_t off = 0;
  __hip_bfloat16* u    = (__hip_bfloat16*)(ws + off); off += U_B;
  __hip_bfloat16* hA   = (__hip_bfloat16*)(ws + off); off += H_B;
  __hip_bfloat16* hB   = (__hip_bfloat16*)(ws + off); off += H_B;
  __hip_bfloat16* Wt   = (__hip_bfloat16*)(ws + off); off += WT_B;
  __hip_bfloat16* WtO  = (__hip_bfloat16*)(ws + off); off += WTO_B;
  __hip_bfloat16* WcT  = (__hip_bfloat16*)(ws + off); off += WC_B;
  float* bc  = (float*)(ws + off); off += BC_B;
  __hip_bfloat16* xb   = (__hip_bfloat16*)(ws + off); off += XB_B;
  float* Pa  = (float*)(ws + off); off += AB_B;
  float* Pb  = (float*)(ws + off); off += AB_B;
  float* Cin = (float*)(ws + off); off += AB_B;

  prep_weights<<<1860, 256, 0, stream>>>(W_l, W_out, W_in, b_in, b_l,
                                         Wt, WtO, WcT, bc);
  cast_x<<<M_ROWS * 8 / 256, 256, 0, stream>>>(x, xb);

  // layer 0: u = xb @ WcT^T + bc   (input GEMM folded in; K=64)
  // 3072 tiles, 1024 persistent blocks x 3 tiles (one generation, 4/CU)
  gemm_mfma<64, 0, 3><<<1024, 256, 0, stream>>>(xb, WcT, bc, u);
  scan_p1<<<32 * NCHUNK, 256, 0, stream>>>(u, Pa, Pb);
  scan_p2<<<32, 256, 0, stream>>>(Pa, Pb, Cin);
  scan_p3<<<32 * NCHUNK, 256, 0, stream>>>(u, Cin, hB);

  // layer 1
  gemm_mfma<256, 0, 3><<<1024, 256, 0, stream>>>(hB, Wt + 768 * 256,
                                                 b_l + 768, u);
  scan_p1<<<32 * NCHUNK, 256, 0, stream>>>(u, Pa, Pb);
  scan_p2<<<32, 256, 0, stream>>>(Pa, Pb, Cin);
  scan_p3<<<32 * NCHUNK, 256, 0, stream>>>(u, Cin, hA);

  // output GEMM (512 tiles, non-persistent)
  gemm_mfma<256, 1, 1><<<M_ROWS / 128, 256, 0, stream>>>(hA, WtO, b_out, d_out);

  (void)in_sizes; (void)n_in; (void)out_size; (void)ws_size;
}